// Round 5
// baseline (177.472 us; speedup 1.0000x reference)
//
#include <hip/hip_runtime.h>

#define NUM_NODES 100000
#define NUM_EDGES 400000
#define F_IN 16
#define F_EDGE 8
#define EMB 16
#define NUM_GRAPHS 256

#define ET 5                                           // 64-edge tiles per block
#define TILE_E 64
#define EDGE_BLOCKS (NUM_EDGES / (TILE_E * ET))        // 1250

// ---------------------------------------------------------------------------
// Workspace (zeroed each launch): sums : NUM_NODES*EMB f32, cnt : NUM_NODES f32
// ---------------------------------------------------------------------------

// v6 edge kernel. v5 post-mortem: the fenced X[4][16] register tile (~100
// live VGPR) exceeded what the allocator will hold (VGPR=84) -> partial
// scratch spill, visible as WRITE_SIZE 37.5->73.7 MB and FETCH +19 MB.
// Fix: keep 4-edge LDS amortization (32 ds_read_b128/wave-tile serve 16
// edges: LDS floor 31->15.6 us, balancing ~15 us VALU floor) but DROP the
// X register tile: an x row is exactly one 64B cache line, so x[src][i] is
// loaded per-i as a 4B broadcast (16-lane-uniform address). i=0 issued in
// the tile preamble pulls the line into L1; i=1..15 are L1 hits hidden
// under the 32 FMAs each i issues. Fenced live state ~76 regs.
// Invariants kept: o = tid&15 (row-atomic coalescing); per-(edge,o) FMA
// order identical to v1/v3 (bit-exact); upfront src preload behind fence.
__global__ __launch_bounds__(256, 3) void edge_kernel(
    const float* __restrict__ x, const int* __restrict__ ei,
    const float* __restrict__ ea, const float* __restrict__ nn1_w,
    const float* __restrict__ nn1_b, float* __restrict__ sums,
    float* __restrict__ cnt)
{
    __shared__ float wtp[256 * 12];   // row r=(i*16+o): 8 weights + 4 pad
    __shared__ float btp[16 * 20];    // btp[o*20+i]

    const int tid = threadIdx.x;
    const int eL  = tid >> 4;         // 0..15
    const int o   = tid & 15;         // LOW bits: atomic-coalescing invariant
    const int eb0 = blockIdx.x * (TILE_E * ET);

    // ---- all src indices issued FIRST (latency hides under weight staging)
    int srcT[ET][4];
    #pragma unroll
    for (int t = 0; t < ET; t++)
        #pragma unroll
        for (int q = 0; q < 4; q++)
            srcT[t][q] = ei[eb0 + t * TILE_E + q * 16 + eL];
    __builtin_amdgcn_sched_barrier(0);   // pin: src loads issue first

    // ---- stage weights, vectorized (row stride 12 floats: 2-way bank = free)
    {
        const float4 w0 = *(const float4*)&nn1_w[tid * 8];
        const float4 w1 = *(const float4*)&nn1_w[tid * 8 + 4];
        *(float4*)&wtp[tid * 12]     = w0;
        *(float4*)&wtp[tid * 12 + 4] = w1;
    }
    btp[(tid & 15) * 20 + (tid >> 4)] = nn1_b[tid];   // tid = i*16+o
    __syncthreads();                                   // the ONLY barrier

    float br[F_IN];
    #pragma unroll
    for (int r = 0; r < 4; r++) {
        const float4 b4 = *(const float4*)&btp[o * 20 + 4 * r];
        br[4 * r + 0] = b4.x; br[4 * r + 1] = b4.y;
        br[4 * r + 2] = b4.z; br[4 * r + 3] = b4.w;
    }

    #pragma unroll
    for (int t = 0; t < ET; t++) {
        // ---- tile preamble: dst, ea, and the FIRST x element per edge
        //      (brings each edge's 64B x row into L1). Small fenced live
        //      set: a0/a1 (32) + dst (4) + xi (4) + srcT (20) + br (16).
        int dst[4];
        float4 a0[4], a1[4];
        float xi[4];
        #pragma unroll
        for (int q = 0; q < 4; q++) {
            const int eI = eb0 + t * TILE_E + q * 16 + eL;
            dst[q] = ei[NUM_EDGES + eI];
            a0[q]  = *(const float4*)&ea[eI * 8];
            a1[q]  = *(const float4*)&ea[eI * 8 + 4];
            xi[q]  = x[srcT[t][q] * 16];     // line-fill for i=0..15
        }
        __builtin_amdgcn_sched_barrier(0);   // preamble loads stay above compute

        // ---- compute: one LDS weight read per i serves 4 edges; next i's
        //      x element prefetched per iteration (L1 hit, hidden by FMAs).
        float acc[4] = {0.f, 0.f, 0.f, 0.f};
        #pragma unroll
        for (int i = 0; i < F_IN; i++) {
            float xn[4];
            if (i < F_IN - 1) {
                #pragma unroll
                for (int q = 0; q < 4; q++)
                    xn[q] = x[srcT[t][q] * 16 + i + 1];
            }
            const float* wr = &wtp[(i * 16 + o) * 12];
            const float4 w0 = *(const float4*)wr;
            const float4 w1 = *(const float4*)(wr + 4);
            #pragma unroll
            for (int q = 0; q < 4; q++) {
                float u = br[i];
                u = fmaf(a0[q].x, w0.x, u); u = fmaf(a0[q].y, w0.y, u);
                u = fmaf(a0[q].z, w0.z, u); u = fmaf(a0[q].w, w0.w, u);
                u = fmaf(a1[q].x, w1.x, u); u = fmaf(a1[q].y, w1.y, u);
                u = fmaf(a1[q].z, w1.z, u); u = fmaf(a1[q].w, w1.w, u);
                acc[q] = fmaf(xi[q], fmaxf(u, 0.f), acc[q]);
            }
            if (i < F_IN - 1) {
                #pragma unroll
                for (int q = 0; q < 4; q++) xi[q] = xn[q];
            }
        }

        // ---- coalesced row atomics: per instruction, 4 whole 64B rows
        //      (16 contiguous lanes each).
        #pragma unroll
        for (int q = 0; q < 4; q++)
            atomicAdd(&sums[dst[q] * 16 + o], acc[q]);
        if (o == 0) {
            #pragma unroll
            for (int q = 0; q < 4; q++)
                atomicAdd(&cnt[dst[q]], 1.f);
        }
    }
}

// One block per GRAPH (batch is sorted). Replaces node_kernel + head_kernel.
// Binary-search the node range [start,end); stream nodes in 16-node tiles:
// thread (j = tid>>4, o = tid&15) computes h[base+j][o]; the x row is
// accessed via intra-wave shuffle (wave = 4 j-values x 16 o-values, so
// x[n][i] lives in lane ((j&3)<<4)|i ) -- no LDS staging, no barriers, no
// serial flusher, and NO pooling atomics: per-thread register accumulators
// -> wave tree-reduce -> cross-wave LDS reduce -> fused head MLP -> out[g].
// (Unchanged: passed R3/R4 with absmax 0.0; ~5-10 us, not the lever.)
__global__ __launch_bounds__(256) void graph_kernel(
    const float* __restrict__ x, const int* __restrict__ batch,
    const float* __restrict__ root_w, const float* __restrict__ conv_b,
    const float* __restrict__ sums, const float* __restrict__ cnt,
    const float* __restrict__ lin1_w, const float* __restrict__ lin1_b,
    const float* __restrict__ lin2_w, const float* __restrict__ lin2_b,
    float* __restrict__ out)
{
    __shared__ float redM[4][16];
    __shared__ float redS[4][16];

    const int g   = blockIdx.x;
    const int tid = threadIdx.x;
    const int j   = tid >> 4;
    const int o   = tid & 15;
    const int jw  = j & 3;             // j within the 64-lane wave

    // root_w row o into registers: rwr[i] = root_w[o*16+i]
    float rwr[F_IN];
    #pragma unroll
    for (int r = 0; r < 4; r++) {
        const float4 v = *(const float4*)&root_w[o * 16 + 4 * r];
        rwr[4*r+0] = v.x; rwr[4*r+1] = v.y; rwr[4*r+2] = v.z; rwr[4*r+3] = v.w;
    }
    const float cb = conv_b[o];

    // Interleaved binary searches (batch sorted, block-uniform -> no
    // divergence; the two dependent-load chains overlap each other):
    //   start = lower_bound(batch, g), end = lower_bound(batch, g+1)
    int lo0 = 0, hi0 = NUM_NODES, lo1 = 0, hi1 = NUM_NODES;
    while (lo0 < hi0 || lo1 < hi1) {
        const int m0 = (lo0 + hi0) >> 1;
        const int m1 = (lo1 + hi1) >> 1;
        int b0 = 0, b1 = 0;
        if (lo0 < hi0) b0 = batch[m0];
        if (lo1 < hi1) b1 = batch[m1];
        if (lo0 < hi0) { if (b0 < g)     lo0 = m0 + 1; else hi0 = m0; }
        if (lo1 < hi1) { if (b1 < g + 1) lo1 = m1 + 1; else hi1 = m1; }
    }
    const int start = lo0, end = lo1;

    float am = 0.f, asum = 0.f;        // h >= 0, so 0 is a valid max identity

    // software-pipelined main loop (prefetch next tile's 3 loads)
    int base = start;
    float xv = 0.f, sv = 0.f, cv = 1.f;
    if (base < end) {
        const int n = base + j;
        const bool v = n < end;
        xv = v ? x[n * 16 + o]    : 0.f;
        sv = v ? sums[n * 16 + o] : 0.f;
        cv = v ? cnt[n]           : 1.f;
    }
    while (base < end) {
        const int nbase = base + 16;
        float xv1 = 0.f, sv1 = 0.f, cv1 = 1.f;
        if (nbase < end) {
            const int n1 = nbase + j;
            const bool v1 = n1 < end;
            xv1 = v1 ? x[n1 * 16 + o]    : 0.f;
            sv1 = v1 ? sums[n1 * 16 + o] : 0.f;
            cv1 = v1 ? cnt[n1]           : 1.f;
        }
        __builtin_amdgcn_sched_barrier(0);   // prefetch issues before compute

        // h-FMA order identical to old node_kernel (bit-exact per element)
        float a = cb + sv / fmaxf(cv, 1.f);
        #pragma unroll
        for (int i = 0; i < F_IN; i++)
            a = fmaf(__shfl(xv, (jw << 4) | i, 64), rwr[i], a);
        const bool v = (base + j) < end;
        const float h = v ? fmaxf(a, 0.f) : 0.f;
        am = fmaxf(am, h);
        asum += h;

        xv = xv1; sv = sv1; cv = cv1;
        base = nbase;
    }

    // reduce over j: butterfly within wave (j&3), then across 4 waves via LDS
    am   = fmaxf(am, __shfl_xor(am, 16, 64));
    am   = fmaxf(am, __shfl_xor(am, 32, 64));
    asum = asum + __shfl_xor(asum, 16, 64);
    asum = asum + __shfl_xor(asum, 32, 64);
    const int w = tid >> 6;
    if ((tid & 63) < 16) { redM[w][o] = am; redS[w][o] = asum; }
    __syncthreads();

    if (tid < 64) {                     // wave 0: final reduce + head MLP
        const int k = tid & 15;
        const float amF = fmaxf(fmaxf(redM[0][k], redM[1][k]),
                                fmaxf(redM[2][k], redM[3][k]));
        const float asF = (redS[0][k] + redS[1][k]) + (redS[2][k] + redS[3][k]);
        const float c   = fmaxf((float)(end - start), 1.f);
        const float mnF = asF / c;

        // lane k computes a_k; inner cc order matches old head_kernel
        float a = lin1_b[k];
        #pragma unroll
        for (int cc = 0; cc < 16; cc++)
            a = fmaf(__shfl(amF, cc, 64), lin1_w[k * 32 + cc], a);
        #pragma unroll
        for (int cc = 0; cc < 16; cc++)
            a = fmaf(__shfl(mnF, cc, 64), lin1_w[k * 32 + 16 + cc], a);
        const float ra = fmaxf(a, 0.f);

        // serial k-accumulation (same order as old head_kernel)
        float acc = lin2_b[0];
        #pragma unroll
        for (int k2 = 0; k2 < 16; k2++)
            acc = fmaf(__shfl(ra, k2, 64), lin2_w[k2], acc);
        if (tid == 0) out[g] = acc;
    }
}

extern "C" void kernel_launch(void* const* d_in, const int* in_sizes, int n_in,
                              void* d_out, int out_size, void* d_ws, size_t ws_size,
                              hipStream_t stream) {
    const float* x      = (const float*)d_in[0];
    const int*   ei     = (const int*)d_in[1];
    const float* ea     = (const float*)d_in[2];
    const int*   batch  = (const int*)d_in[3];
    const float* nn1_w  = (const float*)d_in[4];
    const float* nn1_b  = (const float*)d_in[5];
    const float* root_w = (const float*)d_in[6];
    const float* conv_b = (const float*)d_in[7];
    const float* lin1_w = (const float*)d_in[8];
    const float* lin1_b = (const float*)d_in[9];
    const float* lin2_w = (const float*)d_in[10];
    const float* lin2_b = (const float*)d_in[11];
    float* out = (float*)d_out;

    float* sums = (float*)d_ws;
    float* cnt  = sums + (size_t)NUM_NODES * EMB;

    const size_t zero_bytes = sizeof(float) * ((size_t)NUM_NODES * EMB + NUM_NODES);
    hipMemsetAsync(d_ws, 0, zero_bytes, stream);

    edge_kernel<<<EDGE_BLOCKS, 256, 0, stream>>>(x, ei, ea, nn1_w, nn1_b, sums, cnt);
    graph_kernel<<<NUM_GRAPHS, 256, 0, stream>>>(
        x, batch, root_w, conv_b, sums, cnt,
        lin1_w, lin1_b, lin2_w, lin2_b, out);
}

// Round 6
// 160.408 us; speedup vs baseline: 1.1064x; 1.1064x over previous
//
#include <hip/hip_runtime.h>

#define NUM_NODES 100000
#define NUM_EDGES 400000
#define F_IN 16
#define F_EDGE 8
#define EMB 16
#define NUM_GRAPHS 256

#define ET 5                                           // 64-edge tiles per block
#define TILE_E 64
#define EDGE_BLOCKS (NUM_EDGES / (TILE_E * ET))        // 1250

// ---------------------------------------------------------------------------
// Workspace (zeroed each launch): sums : NUM_NODES*EMB f32, cnt : NUM_NODES f32
// ---------------------------------------------------------------------------

// v7 edge kernel. v5/v6 post-mortem: per-tile sched_barrier(0) + 4-edge
// unrolled tile state made the allocator SPILL instead of pipeline — both
// rounds produced byte-identical excess traffic (WRITE 37.5->73.7 MB,
// FETCH +19 MB) at VGPR=84. v2 showed the inverse: unfenced, the compiler
// sinks loads to their uses and never spills (VGPR 68). So v7 keeps the
// 4-edge LDS amortization (32 ds_read_b128/wave-tile serve 16 edges: LDS
// pipe 31 -> 15.6 us, balancing the ~15-17 us VALU floor — the arithmetic
// that motivated v5) and DELETES the per-tile fences. Only the upfront
// srcT preload fence remains (proven safe at VGPR 80 in v3; 20 regs).
// Invariants kept: o = tid&15 (row-atomic coalescing: 16 contiguous lanes
// per 64B sums row); per-(edge,o) FMA order identical to v1/v3 (bit-exact).
__global__ __launch_bounds__(256, 3) void edge_kernel(
    const float* __restrict__ x, const int* __restrict__ ei,
    const float* __restrict__ ea, const float* __restrict__ nn1_w,
    const float* __restrict__ nn1_b, float* __restrict__ sums,
    float* __restrict__ cnt)
{
    __shared__ float wtp[256 * 12];   // row r=(i*16+o): 8 weights + 4 pad
    __shared__ float btp[16 * 20];    // btp[o*20+i]

    const int tid = threadIdx.x;
    const int eL  = tid >> 4;         // 0..15
    const int o   = tid & 15;         // LOW bits: atomic-coalescing invariant
    const int eb0 = blockIdx.x * (TILE_E * ET);

    // ---- all src indices issued FIRST (latency hides under weight staging)
    int srcT[ET][4];
    #pragma unroll
    for (int t = 0; t < ET; t++)
        #pragma unroll
        for (int q = 0; q < 4; q++)
            srcT[t][q] = ei[eb0 + t * TILE_E + q * 16 + eL];
    __builtin_amdgcn_sched_barrier(0);   // pin: src loads issue first (safe, 20 regs)

    // ---- stage weights, vectorized (row stride 12 floats: 2-way bank = free)
    {
        const float4 w0 = *(const float4*)&nn1_w[tid * 8];
        const float4 w1 = *(const float4*)&nn1_w[tid * 8 + 4];
        *(float4*)&wtp[tid * 12]     = w0;
        *(float4*)&wtp[tid * 12 + 4] = w1;
    }
    btp[(tid & 15) * 20 + (tid >> 4)] = nn1_b[tid];   // tid = i*16+o
    __syncthreads();                                   // the ONLY barrier

    float br[F_IN];
    #pragma unroll
    for (int r = 0; r < 4; r++) {
        const float4 b4 = *(const float4*)&btp[o * 20 + 4 * r];
        br[4 * r + 0] = b4.x; br[4 * r + 1] = b4.y;
        br[4 * r + 2] = b4.z; br[4 * r + 3] = b4.w;
    }

    #pragma unroll
    for (int t = 0; t < ET; t++) {
        // ---- tile t loads: NO fence — compiler schedules/sinks these to
        //      keep live ranges short (v2 evidence: that's what it does,
        //      and it never spills when allowed to).
        int dst[4];
        float4 a0[4], a1[4];
        float X[4][F_IN];
        #pragma unroll
        for (int q = 0; q < 4; q++) {
            const int eI = eb0 + t * TILE_E + q * 16 + eL;
            dst[q] = ei[NUM_EDGES + eI];
            a0[q]  = *(const float4*)&ea[eI * 8];
            a1[q]  = *(const float4*)&ea[eI * 8 + 4];
            #pragma unroll
            for (int r = 0; r < 4; r++) {
                const float4 v = *(const float4*)&x[srcT[t][q] * 16 + 4 * r];
                X[q][4*r+0] = v.x; X[q][4*r+1] = v.y;
                X[q][4*r+2] = v.z; X[q][4*r+3] = v.w;
            }
        }

        // ---- compute: one LDS weight read per i serves all 4 edges.
        //      4 independent FMA chains (q) give intra-thread ILP.
        float acc[4] = {0.f, 0.f, 0.f, 0.f};
        #pragma unroll
        for (int i = 0; i < F_IN; i++) {
            const float* wr = &wtp[(i * 16 + o) * 12];
            const float4 w0 = *(const float4*)wr;
            const float4 w1 = *(const float4*)(wr + 4);
            #pragma unroll
            for (int q = 0; q < 4; q++) {
                float u = br[i];
                u = fmaf(a0[q].x, w0.x, u); u = fmaf(a0[q].y, w0.y, u);
                u = fmaf(a0[q].z, w0.z, u); u = fmaf(a0[q].w, w0.w, u);
                u = fmaf(a1[q].x, w1.x, u); u = fmaf(a1[q].y, w1.y, u);
                u = fmaf(a1[q].z, w1.z, u); u = fmaf(a1[q].w, w1.w, u);
                acc[q] = fmaf(X[q][i], fmaxf(u, 0.f), acc[q]);
            }
        }

        // ---- coalesced row atomics: per instruction, 4 whole 64B rows
        //      (16 contiguous lanes each).
        #pragma unroll
        for (int q = 0; q < 4; q++)
            atomicAdd(&sums[dst[q] * 16 + o], acc[q]);
        if (o == 0) {
            #pragma unroll
            for (int q = 0; q < 4; q++)
                atomicAdd(&cnt[dst[q]], 1.f);
        }
    }
}

// One block per GRAPH (batch is sorted). Replaces node_kernel + head_kernel.
// Binary-search the node range [start,end); stream nodes in 16-node tiles:
// thread (j = tid>>4, o = tid&15) computes h[base+j][o]; the x row is
// accessed via intra-wave shuffle (wave = 4 j-values x 16 o-values, so
// x[n][i] lives in lane ((j&3)<<4)|i ) -- no LDS staging, no barriers, no
// serial flusher, and NO pooling atomics: per-thread register accumulators
// -> wave tree-reduce -> cross-wave LDS reduce -> fused head MLP -> out[g].
// (Unchanged: passed R3-R5 with absmax 0.0; ~5-10 us, not the lever.)
__global__ __launch_bounds__(256) void graph_kernel(
    const float* __restrict__ x, const int* __restrict__ batch,
    const float* __restrict__ root_w, const float* __restrict__ conv_b,
    const float* __restrict__ sums, const float* __restrict__ cnt,
    const float* __restrict__ lin1_w, const float* __restrict__ lin1_b,
    const float* __restrict__ lin2_w, const float* __restrict__ lin2_b,
    float* __restrict__ out)
{
    __shared__ float redM[4][16];
    __shared__ float redS[4][16];

    const int g   = blockIdx.x;
    const int tid = threadIdx.x;
    const int j   = tid >> 4;
    const int o   = tid & 15;
    const int jw  = j & 3;             // j within the 64-lane wave

    // root_w row o into registers: rwr[i] = root_w[o*16+i]
    float rwr[F_IN];
    #pragma unroll
    for (int r = 0; r < 4; r++) {
        const float4 v = *(const float4*)&root_w[o * 16 + 4 * r];
        rwr[4*r+0] = v.x; rwr[4*r+1] = v.y; rwr[4*r+2] = v.z; rwr[4*r+3] = v.w;
    }
    const float cb = conv_b[o];

    // Interleaved binary searches (batch sorted, block-uniform -> no
    // divergence; the two dependent-load chains overlap each other):
    //   start = lower_bound(batch, g), end = lower_bound(batch, g+1)
    int lo0 = 0, hi0 = NUM_NODES, lo1 = 0, hi1 = NUM_NODES;
    while (lo0 < hi0 || lo1 < hi1) {
        const int m0 = (lo0 + hi0) >> 1;
        const int m1 = (lo1 + hi1) >> 1;
        int b0 = 0, b1 = 0;
        if (lo0 < hi0) b0 = batch[m0];
        if (lo1 < hi1) b1 = batch[m1];
        if (lo0 < hi0) { if (b0 < g)     lo0 = m0 + 1; else hi0 = m0; }
        if (lo1 < hi1) { if (b1 < g + 1) lo1 = m1 + 1; else hi1 = m1; }
    }
    const int start = lo0, end = lo1;

    float am = 0.f, asum = 0.f;        // h >= 0, so 0 is a valid max identity

    // software-pipelined main loop (prefetch next tile's 3 loads)
    int base = start;
    float xv = 0.f, sv = 0.f, cv = 1.f;
    if (base < end) {
        const int n = base + j;
        const bool v = n < end;
        xv = v ? x[n * 16 + o]    : 0.f;
        sv = v ? sums[n * 16 + o] : 0.f;
        cv = v ? cnt[n]           : 1.f;
    }
    while (base < end) {
        const int nbase = base + 16;
        float xv1 = 0.f, sv1 = 0.f, cv1 = 1.f;
        if (nbase < end) {
            const int n1 = nbase + j;
            const bool v1 = n1 < end;
            xv1 = v1 ? x[n1 * 16 + o]    : 0.f;
            sv1 = v1 ? sums[n1 * 16 + o] : 0.f;
            cv1 = v1 ? cnt[n1]           : 1.f;
        }
        __builtin_amdgcn_sched_barrier(0);   // prefetch issues before compute

        // h-FMA order identical to old node_kernel (bit-exact per element)
        float a = cb + sv / fmaxf(cv, 1.f);
        #pragma unroll
        for (int i = 0; i < F_IN; i++)
            a = fmaf(__shfl(xv, (jw << 4) | i, 64), rwr[i], a);
        const bool v = (base + j) < end;
        const float h = v ? fmaxf(a, 0.f) : 0.f;
        am = fmaxf(am, h);
        asum += h;

        xv = xv1; sv = sv1; cv = cv1;
        base = nbase;
    }

    // reduce over j: butterfly within wave (j&3), then across 4 waves via LDS
    am   = fmaxf(am, __shfl_xor(am, 16, 64));
    am   = fmaxf(am, __shfl_xor(am, 32, 64));
    asum = asum + __shfl_xor(asum, 16, 64);
    asum = asum + __shfl_xor(asum, 32, 64);
    const int w = tid >> 6;
    if ((tid & 63) < 16) { redM[w][o] = am; redS[w][o] = asum; }
    __syncthreads();

    if (tid < 64) {                     // wave 0: final reduce + head MLP
        const int k = tid & 15;
        const float amF = fmaxf(fmaxf(redM[0][k], redM[1][k]),
                                fmaxf(redM[2][k], redM[3][k]));
        const float asF = (redS[0][k] + redS[1][k]) + (redS[2][k] + redS[3][k]);
        const float c   = fmaxf((float)(end - start), 1.f);
        const float mnF = asF / c;

        // lane k computes a_k; inner cc order matches old head_kernel
        float a = lin1_b[k];
        #pragma unroll
        for (int cc = 0; cc < 16; cc++)
            a = fmaf(__shfl(amF, cc, 64), lin1_w[k * 32 + cc], a);
        #pragma unroll
        for (int cc = 0; cc < 16; cc++)
            a = fmaf(__shfl(mnF, cc, 64), lin1_w[k * 32 + 16 + cc], a);
        const float ra = fmaxf(a, 0.f);

        // serial k-accumulation (same order as old head_kernel)
        float acc = lin2_b[0];
        #pragma unroll
        for (int k2 = 0; k2 < 16; k2++)
            acc = fmaf(__shfl(ra, k2, 64), lin2_w[k2], acc);
        if (tid == 0) out[g] = acc;
    }
}

extern "C" void kernel_launch(void* const* d_in, const int* in_sizes, int n_in,
                              void* d_out, int out_size, void* d_ws, size_t ws_size,
                              hipStream_t stream) {
    const float* x      = (const float*)d_in[0];
    const int*   ei     = (const int*)d_in[1];
    const float* ea     = (const float*)d_in[2];
    const int*   batch  = (const int*)d_in[3];
    const float* nn1_w  = (const float*)d_in[4];
    const float* nn1_b  = (const float*)d_in[5];
    const float* root_w = (const float*)d_in[6];
    const float* conv_b = (const float*)d_in[7];
    const float* lin1_w = (const float*)d_in[8];
    const float* lin1_b = (const float*)d_in[9];
    const float* lin2_w = (const float*)d_in[10];
    const float* lin2_b = (const float*)d_in[11];
    float* out = (float*)d_out;

    float* sums = (float*)d_ws;
    float* cnt  = sums + (size_t)NUM_NODES * EMB;

    const size_t zero_bytes = sizeof(float) * ((size_t)NUM_NODES * EMB + NUM_NODES);
    hipMemsetAsync(d_ws, 0, zero_bytes, stream);

    edge_kernel<<<EDGE_BLOCKS, 256, 0, stream>>>(x, ei, ea, nn1_w, nn1_b, sums, cnt);
    graph_kernel<<<NUM_GRAPHS, 256, 0, stream>>>(
        x, batch, root_w, conv_b, sums, cnt,
        lin1_w, lin1_b, lin2_w, lin2_b, out);
}

// Round 7
// 157.446 us; speedup vs baseline: 1.1272x; 1.0188x over previous
//
#include <hip/hip_runtime.h>

#define NUM_NODES 100000
#define NUM_EDGES 400000
#define F_IN 16
#define F_EDGE 8
#define EMB 16
#define NUM_GRAPHS 256

#define EDGE_TILES 5                                   // 32-edge tiles per block
#define EDGE_BLOCKS (NUM_EDGES / (32 * EDGE_TILES))    // 2500

// ---------------------------------------------------------------------------
// Workspace (zeroed each launch): sums : NUM_NODES*EMB f32, cnt : NUM_NODES f32
// ---------------------------------------------------------------------------

// v8 edge kernel = v3's edge kernel, verbatim (measured 50.3 us, VGPR 80,
// zero spill, WRITE 37.5 MB). Session ledger on why this exact shape:
//  - 4-edge amortization (v5/v6/v7): allocator anchors at 84 VGPR
//    (512/6 waves) and spills the X[4][16] tile every time -> +12..36 MB
//    WRITE, 73-90 us. Three structurally different attempts, same result.
//  - o = tid&15 invariant: 16 contiguous lanes cover one 64B sums row per
//    atomic instruction (v4 violated it: WRITE doubled).
//  - fences: ONLY coarse ones, and only with fenced live state < ~60 regs
//    (v3's 2-edge dbuf). Bigger fenced sets spill (v5/v6).
__global__ __launch_bounds__(256, 3) void edge_kernel(
    const float* __restrict__ x, const int* __restrict__ ei,
    const float* __restrict__ ea, const float* __restrict__ nn1_w,
    const float* __restrict__ nn1_b, float* __restrict__ sums,
    float* __restrict__ cnt)
{
    __shared__ float wtp[256 * 12];   // row r=(i*16+o): 8 weights + 4 pad
    __shared__ float btp[16 * 20];    // btp[o*20+i]

    const int tid = threadIdx.x;
    const int eL  = tid >> 4;
    const int o   = tid & 15;         // LOW bits: atomic-coalescing invariant
    const int eb0 = blockIdx.x * EDGE_TILES * 32;

    // ---- issue all src-index loads immediately (latency hides under staging)
    int srcA[EDGE_TILES], srcB[EDGE_TILES];
    #pragma unroll
    for (int t = 0; t < EDGE_TILES; t++) {
        srcA[t] = ei[eb0 + t * 32 + eL];
        srcB[t] = ei[eb0 + t * 32 + 16 + eL];
    }
    __builtin_amdgcn_sched_barrier(0);   // pin: src loads issue FIRST

    // ---- stage weights, vectorized (row stride 12 floats: 2-way bank = free)
    {
        const float4 w0 = *(const float4*)&nn1_w[tid * 8];
        const float4 w1 = *(const float4*)&nn1_w[tid * 8 + 4];
        *(float4*)&wtp[tid * 12]     = w0;
        *(float4*)&wtp[tid * 12 + 4] = w1;
    }
    btp[(tid & 15) * 20 + (tid >> 4)] = nn1_b[tid];   // tid = i*16+o
    __syncthreads();                                   // the ONLY barrier

    float br[F_IN];
    #pragma unroll
    for (int r = 0; r < 4; r++) {
        const float4 b4 = *(const float4*)&btp[o * 20 + 4 * r];
        br[4 * r + 0] = b4.x; br[4 * r + 1] = b4.y;
        br[4 * r + 2] = b4.z; br[4 * r + 3] = b4.w;
    }

    // ---- double-buffered tile state (p = even tiles, q = odd tiles)
    float4 pA00, pA01, pA10, pA11; float pX0[16], pX1[16]; int pDA, pDB;
    float4 qA00, qA01, qA10, qA11; float qX0[16], qX1[16]; int qDA, qDB;

#define LOAD_TILE(T, A00, A01, A10, A11, X0, X1, DA, DB) do {               \
        const int eA_ = eb0 + (T) * 32 + eL;                                \
        const int eB_ = eA_ + 16;                                           \
        DA = ei[NUM_EDGES + eA_];                                           \
        DB = ei[NUM_EDGES + eB_];                                           \
        A00 = *(const float4*)&ea[eA_ * 8];                                 \
        A01 = *(const float4*)&ea[eA_ * 8 + 4];                             \
        A10 = *(const float4*)&ea[eB_ * 8];                                 \
        A11 = *(const float4*)&ea[eB_ * 8 + 4];                             \
        _Pragma("unroll")                                                   \
        for (int r = 0; r < 4; r++) {                                       \
            const float4 v0 = *(const float4*)&x[srcA[T] * 16 + 4 * r];     \
            const float4 v1 = *(const float4*)&x[srcB[T] * 16 + 4 * r];     \
            X0[4*r+0] = v0.x; X0[4*r+1] = v0.y;                             \
            X0[4*r+2] = v0.z; X0[4*r+3] = v0.w;                             \
            X1[4*r+0] = v1.x; X1[4*r+1] = v1.y;                             \
            X1[4*r+2] = v1.z; X1[4*r+3] = v1.w;                             \
        }                                                                   \
    } while (0)

#define COMPUTE_TILE(A00, A01, A10, A11, X0, X1, DA, DB) do {               \
        float acc0 = 0.f, acc1 = 0.f;                                       \
        _Pragma("unroll")                                                   \
        for (int i = 0; i < F_IN; i++) {                                    \
            const float* wr = &wtp[(i * 16 + o) * 12];                      \
            const float4 w0 = *(const float4*)wr;                           \
            const float4 w1 = *(const float4*)(wr + 4);                     \
            float u = br[i];                                                \
            u = fmaf(A00.x, w0.x, u); u = fmaf(A00.y, w0.y, u);             \
            u = fmaf(A00.z, w0.z, u); u = fmaf(A00.w, w0.w, u);             \
            u = fmaf(A01.x, w1.x, u); u = fmaf(A01.y, w1.y, u);             \
            u = fmaf(A01.z, w1.z, u); u = fmaf(A01.w, w1.w, u);             \
            acc0 = fmaf(X0[i], fmaxf(u, 0.f), acc0);                        \
            float v = br[i];                                                \
            v = fmaf(A10.x, w0.x, v); v = fmaf(A10.y, w0.y, v);             \
            v = fmaf(A10.z, w0.z, v); v = fmaf(A10.w, w0.w, v);             \
            v = fmaf(A11.x, w1.x, v); v = fmaf(A11.y, w1.y, v);             \
            v = fmaf(A11.w, w1.w, v); v = fmaf(A11.z, w1.z, v);             \
            acc1 = fmaf(X1[i], fmaxf(v, 0.f), acc1);                        \
        }                                                                   \
        atomicAdd(&sums[DA * 16 + o], acc0);                                \
        atomicAdd(&sums[DB * 16 + o], acc1);                                \
        if (o == 0) {                                                       \
            atomicAdd(&cnt[DA], 1.f);                                       \
            atomicAdd(&cnt[DB], 1.f);                                       \
        }                                                                   \
    } while (0)

    LOAD_TILE(0, pA00, pA01, pA10, pA11, pX0, pX1, pDA, pDB);
    #pragma unroll
    for (int t = 0; t < EDGE_TILES; t++) {
        if ((t & 1) == 0) {
            if (t + 1 < EDGE_TILES)
                LOAD_TILE(t + 1, qA00, qA01, qA10, qA11, qX0, qX1, qDA, qDB);
            __builtin_amdgcn_sched_barrier(0);   // loads(t+1) stay above compute(t)
            COMPUTE_TILE(pA00, pA01, pA10, pA11, pX0, pX1, pDA, pDB);
        } else {
            if (t + 1 < EDGE_TILES)
                LOAD_TILE(t + 1, pA00, pA01, pA10, pA11, pX0, pX1, pDA, pDB);
            __builtin_amdgcn_sched_barrier(0);
            COMPUTE_TILE(qA00, qA01, qA10, qA11, qX0, qX1, qDA, qDB);
        }
    }
#undef LOAD_TILE
#undef COMPUTE_TILE
}

// One block per GRAPH (batch is sorted). Replaces node_kernel + head_kernel.
// Binary-search the node range [start,end); stream nodes in 16-node tiles:
// thread (j = tid>>4, o = tid&15) computes h[base+j][o]; the x row is
// accessed via intra-wave shuffle (wave = 4 j-values x 16 o-values, so
// x[n][i] lives in lane ((j&3)<<4)|i ) -- no LDS staging, no barriers, no
// serial flusher, and NO pooling atomics: per-thread register accumulators
// -> wave tree-reduce -> cross-wave LDS reduce -> fused head MLP -> out[g].
// (Unchanged: passed R3-R6 with absmax 0.0; fusion worth ~40 us vs old
// node+head per the R2 vs R6 totals.)
__global__ __launch_bounds__(256) void graph_kernel(
    const float* __restrict__ x, const int* __restrict__ batch,
    const float* __restrict__ root_w, const float* __restrict__ conv_b,
    const float* __restrict__ sums, const float* __restrict__ cnt,
    const float* __restrict__ lin1_w, const float* __restrict__ lin1_b,
    const float* __restrict__ lin2_w, const float* __restrict__ lin2_b,
    float* __restrict__ out)
{
    __shared__ float redM[4][16];
    __shared__ float redS[4][16];

    const int g   = blockIdx.x;
    const int tid = threadIdx.x;
    const int j   = tid >> 4;
    const int o   = tid & 15;
    const int jw  = j & 3;             // j within the 64-lane wave

    // root_w row o into registers: rwr[i] = root_w[o*16+i]
    float rwr[F_IN];
    #pragma unroll
    for (int r = 0; r < 4; r++) {
        const float4 v = *(const float4*)&root_w[o * 16 + 4 * r];
        rwr[4*r+0] = v.x; rwr[4*r+1] = v.y; rwr[4*r+2] = v.z; rwr[4*r+3] = v.w;
    }
    const float cb = conv_b[o];

    // Interleaved binary searches (batch sorted, block-uniform -> no
    // divergence; the two dependent-load chains overlap each other):
    //   start = lower_bound(batch, g), end = lower_bound(batch, g+1)
    int lo0 = 0, hi0 = NUM_NODES, lo1 = 0, hi1 = NUM_NODES;
    while (lo0 < hi0 || lo1 < hi1) {
        const int m0 = (lo0 + hi0) >> 1;
        const int m1 = (lo1 + hi1) >> 1;
        int b0 = 0, b1 = 0;
        if (lo0 < hi0) b0 = batch[m0];
        if (lo1 < hi1) b1 = batch[m1];
        if (lo0 < hi0) { if (b0 < g)     lo0 = m0 + 1; else hi0 = m0; }
        if (lo1 < hi1) { if (b1 < g + 1) lo1 = m1 + 1; else hi1 = m1; }
    }
    const int start = lo0, end = lo1;

    float am = 0.f, asum = 0.f;        // h >= 0, so 0 is a valid max identity

    // software-pipelined main loop (prefetch next tile's 3 loads)
    int base = start;
    float xv = 0.f, sv = 0.f, cv = 1.f;
    if (base < end) {
        const int n = base + j;
        const bool v = n < end;
        xv = v ? x[n * 16 + o]    : 0.f;
        sv = v ? sums[n * 16 + o] : 0.f;
        cv = v ? cnt[n]           : 1.f;
    }
    while (base < end) {
        const int nbase = base + 16;
        float xv1 = 0.f, sv1 = 0.f, cv1 = 1.f;
        if (nbase < end) {
            const int n1 = nbase + j;
            const bool v1 = n1 < end;
            xv1 = v1 ? x[n1 * 16 + o]    : 0.f;
            sv1 = v1 ? sums[n1 * 16 + o] : 0.f;
            cv1 = v1 ? cnt[n1]           : 1.f;
        }
        __builtin_amdgcn_sched_barrier(0);   // prefetch issues before compute

        // h-FMA order identical to old node_kernel (bit-exact per element)
        float a = cb + sv / fmaxf(cv, 1.f);
        #pragma unroll
        for (int i = 0; i < F_IN; i++)
            a = fmaf(__shfl(xv, (jw << 4) | i, 64), rwr[i], a);
        const bool v = (base + j) < end;
        const float h = v ? fmaxf(a, 0.f) : 0.f;
        am = fmaxf(am, h);
        asum += h;

        xv = xv1; sv = sv1; cv = cv1;
        base = nbase;
    }

    // reduce over j: butterfly within wave (j&3), then across 4 waves via LDS
    am   = fmaxf(am, __shfl_xor(am, 16, 64));
    am   = fmaxf(am, __shfl_xor(am, 32, 64));
    asum = asum + __shfl_xor(asum, 16, 64);
    asum = asum + __shfl_xor(asum, 32, 64);
    const int w = tid >> 6;
    if ((tid & 63) < 16) { redM[w][o] = am; redS[w][o] = asum; }
    __syncthreads();

    if (tid < 64) {                     // wave 0: final reduce + head MLP
        const int k = tid & 15;
        const float amF = fmaxf(fmaxf(redM[0][k], redM[1][k]),
                                fmaxf(redM[2][k], redM[3][k]));
        const float asF = (redS[0][k] + redS[1][k]) + (redS[2][k] + redS[3][k]);
        const float c   = fmaxf((float)(end - start), 1.f);
        const float mnF = asF / c;

        // lane k computes a_k; inner cc order matches old head_kernel
        float a = lin1_b[k];
        #pragma unroll
        for (int cc = 0; cc < 16; cc++)
            a = fmaf(__shfl(amF, cc, 64), lin1_w[k * 32 + cc], a);
        #pragma unroll
        for (int cc = 0; cc < 16; cc++)
            a = fmaf(__shfl(mnF, cc, 64), lin1_w[k * 32 + 16 + cc], a);
        const float ra = fmaxf(a, 0.f);

        // serial k-accumulation (same order as old head_kernel)
        float acc = lin2_b[0];
        #pragma unroll
        for (int k2 = 0; k2 < 16; k2++)
            acc = fmaf(__shfl(ra, k2, 64), lin2_w[k2], acc);
        if (tid == 0) out[g] = acc;
    }
}

extern "C" void kernel_launch(void* const* d_in, const int* in_sizes, int n_in,
                              void* d_out, int out_size, void* d_ws, size_t ws_size,
                              hipStream_t stream) {
    const float* x      = (const float*)d_in[0];
    const int*   ei     = (const int*)d_in[1];
    const float* ea     = (const float*)d_in[2];
    const int*   batch  = (const int*)d_in[3];
    const float* nn1_w  = (const float*)d_in[4];
    const float* nn1_b  = (const float*)d_in[5];
    const float* root_w = (const float*)d_in[6];
    const float* conv_b = (const float*)d_in[7];
    const float* lin1_w = (const float*)d_in[8];
    const float* lin1_b = (const float*)d_in[9];
    const float* lin2_w = (const float*)d_in[10];
    const float* lin2_b = (const float*)d_in[11];
    float* out = (float*)d_out;

    float* sums = (float*)d_ws;
    float* cnt  = sums + (size_t)NUM_NODES * EMB;

    const size_t zero_bytes = sizeof(float) * ((size_t)NUM_NODES * EMB + NUM_NODES);
    hipMemsetAsync(d_ws, 0, zero_bytes, stream);

    edge_kernel<<<EDGE_BLOCKS, 256, 0, stream>>>(x, ei, ea, nn1_w, nn1_b, sums, cnt);
    graph_kernel<<<NUM_GRAPHS, 256, 0, stream>>>(
        x, batch, root_w, conv_b, sums, cnt,
        lin1_w, lin1_b, lin2_w, lin2_b, out);
}